// Round 4
// baseline (221.022 us; speedup 1.0000x reference)
//
#include <hip/hip_runtime.h>
#include <stdint.h>

#define N_NODES 100000
#define D_FEAT  128
#define N_EDGES 500000
#define HIDDEN  256
#define EPT     64                                   // edges per tile
#define NTILES  ((N_EDGES + EPT - 1) / EPT)          // 7813
#define GRID_MAIN 512                                // 2 blocks/CU

typedef __bf16 bf16x8 __attribute__((ext_vector_type(8)));
typedef __bf16 bf16x4 __attribute__((ext_vector_type(4)));
typedef float  f32x4  __attribute__((ext_vector_type(4)));

__device__ __forceinline__ void gld_lds16(const unsigned short* g, unsigned char* l) {
  __builtin_amdgcn_global_load_lds(
      (const __attribute__((address_space(1))) unsigned int*)g,
      (__attribute__((address_space(3))) unsigned int*)l, 16, 0, 0);
}

__device__ __forceinline__ bf16x8 cvt8(f32x4 lo, f32x4 hi) {
  bf16x8 r;
  r[0] = (__bf16)lo[0]; r[1] = (__bf16)lo[1]; r[2] = (__bf16)lo[2]; r[3] = (__bf16)lo[3];
  r[4] = (__bf16)hi[0]; r[5] = (__bf16)hi[1]; r[6] = (__bf16)hi[2]; r[7] = (__bf16)hi[3];
  return r;
}

// z (f32) -> bf16, vectorized
__global__ void cvt_z(const float* __restrict__ src, unsigned short* __restrict__ dst, int n4) {
  int i = blockIdx.x * blockDim.x + threadIdx.x;
  const int stride = gridDim.x * blockDim.x;
  for (; i < n4; i += stride) {
    const f32x4 v = ((const f32x4*)src)[i];
    bf16x4 o;
    o[0] = (__bf16)v[0]; o[1] = (__bf16)v[1]; o[2] = (__bf16)v[2]; o[3] = (__bf16)v[3];
    ((bf16x4*)dst)[i] = o;
  }
}

// xT = relu(W1 * concatT + b1); out = sigmoid(w2 . x + b2)
// 8 waves; wave w owns hidden rows [32w,32w+32) (a[2][8] = 64 VGPR resident),
// covers all 64 edges (ct=0..3). K-major LDS tile (zero-conflict, from r3):
// 16B unit sbuf[c*1024 + m*16] = F[m][8c..8c+7], staged by global_load_lds.
// Double buffer, ONE barrier per tile, 2 blocks/CU for latency overlap.
__global__ __launch_bounds__(512, 4)
void mlp_main(const int* __restrict__ eidx,
              const unsigned short* __restrict__ z16,   // [N_NODES][128] bf16
              const float* __restrict__ w1f,            // [256][256] f32
              const float* __restrict__ b1,
              const float* __restrict__ w2g,
              const float* __restrict__ b2,
              float* __restrict__ out) {
  __shared__ unsigned char sbuf[2][EPT * 512];          // 2 x 32 KiB
  __shared__ float red[2][8][72];                       // parity x wave x edge(pad)
  __shared__ float b1f[HIDDEN], w2f[HIDDEN];

  const int tid  = threadIdx.x;
  const int w    = tid >> 6;         // wave 0..7 (row group)
  const int l    = tid & 63;
  const int l15  = l & 15;
  const int g    = l >> 4;           // k-slice group 0..3
  const int half = w >> 2;           // staging half: 0 = row node, 1 = col node

  const int is64 = (eidx[1] == 0 && eidx[3] == 0 && eidx[5] == 0);
  const float b2v = b2[0];

  if (tid < HIDDEN) { b1f[tid] = b1[tid]; w2f[tid] = w2g[tid]; }

  // ---- A fragments (W1, f32 -> bf16), register-resident: 64 VGPR ----
  // A[n][k]: n = w*32 + rt*16 + (l&15), k = ks*32 + g*8 .. +7
  bf16x8 a[2][8];
  #pragma unroll
  for (int rt = 0; rt < 2; ++rt) {
    const int n = w * 32 + rt * 16 + l15;
    #pragma unroll
    for (int ks = 0; ks < 8; ++ks) {
      const int k = ks * 32 + g * 8;
      const f32x4 lo = *(const f32x4*)(w1f + n * 256 + k);
      const f32x4 hi = *(const f32x4*)(w1f + n * 256 + k + 4);
      a[rt][ks] = cvt8(lo, hi);
    }
  }

  // per-lane node index (this wave's staging half) for tile t
  auto ldidx = [&](int t) -> int {
    int e = t * EPT + l;
    if (e > N_EDGES - 1) e = N_EDGES - 1;
    return is64 ? eidx[6 * e + 2 + 2 * half] : eidx[3 * e + 1 + half];
  };
  // stage one tile: wave w issues chunks 4w..4w+3 (1 KiB each, linear dest)
  auto stage = [&](int buf, int iv) {
    const unsigned short* src = z16 + (size_t)iv * D_FEAT;
    #pragma unroll
    for (int j = 0; j < 4; ++j) {
      const int c = 4 * w + j;
      gld_lds16(src + ((c & 15) << 3), &sbuf[buf][c << 10]);
    }
  };

  // ---- prologue ----
  const int t0 = blockIdx.x;
  stage(0, ldidx(t0));
  int iv_next = ldidx(t0 + GRID_MAIN);

  int it = 0;
  for (int t = t0; t < NTILES; t += GRID_MAIN, ++it) {
    __syncthreads();                   // drains prev stage (vmcnt) + ds reads
    const int cb = it & 1;

    // stage tile t+1 into the other buffer; prefetch idx for t+2
    stage(cb ^ 1, iv_next);
    iv_next = ldidx(t + 2 * GRID_MAIN);

    // deferred output for tile t-1 (red[par] written before this barrier)
    if (it) {
      const int el = 8 * w + (l & 7);          // wave handles 8 edges
      float v = red[(it - 1) & 1][l >> 3][el]; // lane group = source wave
      v += __shfl_xor(v, 8);
      v += __shfl_xor(v, 16);
      v += __shfl_xor(v, 32);
      const int eg = (t - GRID_MAIN) * EPT + el;
      if (l < 8 && eg < N_EDGES)
        out[eg] = 1.f / (1.f + __expf(-(v + b2v)));
    }

    // ---- MFMA: D[n][m] += sum_k A[n][k] * F[m][k] on buf cb ----
    f32x4 acc[2][4];
    #pragma unroll
    for (int rt = 0; rt < 2; ++rt)
      #pragma unroll
      for (int ct = 0; ct < 4; ++ct)
        acc[rt][ct] = (f32x4){0.f, 0.f, 0.f, 0.f};

    const unsigned char* sb = &sbuf[cb][0];
    #pragma unroll
    for (int ks = 0; ks < 8; ++ks) {
      bf16x8 bf[4];
      #pragma unroll
      for (int ct = 0; ct < 4; ++ct) {
        const int c = ks * 4 + g;                    // k-chunk
        const int m = ct * 16 + l15;                 // edge
        bf[ct] = *(const bf16x8*)(sb + (c << 10) + (m << 4));
      }
      __builtin_amdgcn_s_setprio(1);
      #pragma unroll
      for (int rt = 0; rt < 2; ++rt)
        #pragma unroll
        for (int ct = 0; ct < 4; ++ct)
          acc[rt][ct] = __builtin_amdgcn_mfma_f32_16x16x32_bf16(
              a[rt][ks], bf[ct], acc[rt][ct], 0, 0, 0);
      __builtin_amdgcn_s_setprio(0);
    }

    // ---- epilogue: bias + relu + fc2 partial dot ----
    float p[4] = {0.f, 0.f, 0.f, 0.f};
    #pragma unroll
    for (int rt = 0; rt < 2; ++rt) {
      const int nb = w * 32 + rt * 16 + g * 4;
      const f32x4 bb = *(const f32x4*)&b1f[nb];
      const f32x4 ww = *(const f32x4*)&w2f[nb];
      #pragma unroll
      for (int r = 0; r < 4; ++r) {
        #pragma unroll
        for (int ct = 0; ct < 4; ++ct) {
          float x = acc[rt][ct][r] + bb[r];          // n = w*32+rt*16+g*4+r
          x = fmaxf(x, 0.f);
          p[ct] = fmaf(x, ww[r], p[ct]);
        }
      }
    }
    #pragma unroll
    for (int ct = 0; ct < 4; ++ct) {                 // sum over 4 g-groups
      p[ct] += __shfl_xor(p[ct], 16);
      p[ct] += __shfl_xor(p[ct], 32);
    }
    if (l < 16) {
      #pragma unroll
      for (int ct = 0; ct < 4; ++ct) red[it & 1][w][ct * 16 + l] = p[ct];
    }
  }

  // ---- tail: output last tile ----
  __syncthreads();
  {
    const int tl = t0 + (it - 1) * GRID_MAIN;
    const int el = 8 * w + (l & 7);
    float v = red[(it - 1) & 1][l >> 3][el];
    v += __shfl_xor(v, 8);
    v += __shfl_xor(v, 16);
    v += __shfl_xor(v, 32);
    const int eg = tl * EPT + el;
    if (l < 8 && eg < N_EDGES)
      out[eg] = 1.f / (1.f + __expf(-(v + b2v)));
  }
}

extern "C" void kernel_launch(void* const* d_in, const int* in_sizes, int n_in,
                              void* d_out, int out_size, void* d_ws, size_t ws_size,
                              hipStream_t stream) {
  const float* z    = (const float*)d_in[0];
  const int*   eidx = (const int*)d_in[1];
  const float* fc1w = (const float*)d_in[2];
  const float* fc1b = (const float*)d_in[3];
  const float* fc2w = (const float*)d_in[4];
  const float* fc2b = (const float*)d_in[5];
  float* out = (float*)d_out;

  unsigned short* z16 = (unsigned short*)d_ws;   // 25.6 MB bf16 copy of z

  cvt_z<<<2048, 256, 0, stream>>>(z, z16, N_NODES * D_FEAT / 4);
  mlp_main<<<GRID_MAIN, 512, 0, stream>>>(eidx, z16, fc1w, fc1b, fc2w, fc2b, out);
}

// Round 6
// 183.944 us; speedup vs baseline: 1.2016x; 1.2016x over previous
//
#include <hip/hip_runtime.h>
#include <stdint.h>

#define N_NODES 100000
#define D_FEAT  128
#define N_EDGES 500000
#define HIDDEN  256
#define EPT     64                                   // edges per tile
#define NTILES  ((N_EDGES + EPT - 1) / EPT)          // 7813
#define GRID_MAIN 256

typedef __bf16 bf16x8 __attribute__((ext_vector_type(8)));
typedef __bf16 bf16x4 __attribute__((ext_vector_type(4)));
typedef float  f32x4  __attribute__((ext_vector_type(4)));

__device__ __forceinline__ void gld_lds16(const unsigned short* g, unsigned char* l) {
  __builtin_amdgcn_global_load_lds(
      (const __attribute__((address_space(1))) unsigned int*)g,
      (__attribute__((address_space(3))) unsigned int*)l, 16, 0, 0);
}

__device__ __forceinline__ bf16x8 cvt8(f32x4 lo, f32x4 hi) {
  bf16x8 r;
  r[0] = (__bf16)lo[0]; r[1] = (__bf16)lo[1]; r[2] = (__bf16)lo[2]; r[3] = (__bf16)lo[3];
  r[4] = (__bf16)hi[0]; r[5] = (__bf16)hi[1]; r[6] = (__bf16)hi[2]; r[7] = (__bf16)hi[3];
  return r;
}

// z (f32) -> bf16, vectorized
__global__ void cvt_z(const float* __restrict__ src, unsigned short* __restrict__ dst, int n4) {
  int i = blockIdx.x * blockDim.x + threadIdx.x;
  const int stride = gridDim.x * blockDim.x;
  for (; i < n4; i += stride) {
    const f32x4 v = ((const f32x4*)src)[i];
    bf16x4 o;
    o[0] = (__bf16)v[0]; o[1] = (__bf16)v[1]; o[2] = (__bf16)v[2]; o[3] = (__bf16)v[3];
    ((bf16x4*)dst)[i] = o;
  }
}

// xT = relu(W1 * concatT + b1); out = sigmoid(w2 . x + b2)
// 8 waves; wave w owns hidden rows [32w,32w+32) (a[2][8] register/AGPR resident).
// K-major LDS feature tiles (zero-conflict), QUAD-buffered, staged by
// global_load_lds. Counted-vmcnt pipeline (T3+T4): no vmcnt(0) drain in loop;
// raw s_barrier once per tile; gathers span ~2 iterations.
__global__ __launch_bounds__(512, 2)
void mlp_main(const int* __restrict__ eidx,
              const unsigned short* __restrict__ z16,   // [N_NODES][128] bf16
              const float* __restrict__ w1f,            // [256][256] f32
              const float* __restrict__ b1,
              const float* __restrict__ w2g,
              const float* __restrict__ b2,
              float* __restrict__ out) {
  __shared__ unsigned char sbuf[4][EPT * 512];          // 4 x 32 KiB
  __shared__ float red[2][8][72];                       // parity x wave x edge(pad)
  __shared__ float b1f[HIDDEN], w2f[HIDDEN];

  const int tid  = threadIdx.x;
  const int w    = tid >> 6;         // wave 0..7 (row group)
  const int l    = tid & 63;
  const int l15  = l & 15;
  const int g    = l >> 4;           // k-slice group 0..3
  const int half = w >> 2;           // staging half: 0 = row node, 1 = col node

  const int is64 = (eidx[1] == 0 && eidx[3] == 0 && eidx[5] == 0);
  const float b2v = b2[0];

  if (tid < HIDDEN) { b1f[tid] = b1[tid]; w2f[tid] = w2g[tid]; }

  // ---- A fragments (W1, f32 -> bf16), resident ----
  // A[n][k]: n = w*32 + rt*16 + (l&15), k = ks*32 + g*8 .. +7
  bf16x8 a[2][8];
  #pragma unroll
  for (int rt = 0; rt < 2; ++rt) {
    const int n = w * 32 + rt * 16 + l15;
    #pragma unroll
    for (int ks = 0; ks < 8; ++ks) {
      const int k = ks * 32 + g * 8;
      const f32x4 lo = *(const f32x4*)(w1f + n * 256 + k);
      const f32x4 hi = *(const f32x4*)(w1f + n * 256 + k + 4);
      a[rt][ks] = cvt8(lo, hi);
    }
  }

  // per-lane node index (this wave's staging half) for tile t (edge-clamped)
  auto ldidx = [&](int t) -> int {
    int e = t * EPT + l;
    if (e > N_EDGES - 1) e = N_EDGES - 1;
    return is64 ? eidx[6 * e + 2 + 2 * half] : eidx[3 * e + 1 + half];
  };
  // stage one tile: wave w issues chunks 4w..4w+3 (1 KiB each, linear dest)
  auto stage = [&](int buf, int iv) {
    const unsigned short* src = z16 + (size_t)iv * D_FEAT;
    #pragma unroll
    for (int j = 0; j < 4; ++j) {
      const int c = 4 * w + j;
      gld_lds16(src + ((c & 15) << 3), &sbuf[buf][c << 10]);
    }
  };

  // deferred output for a tile whose partials sit in red[par]
  auto emit = [&](int tile, int par) {
    const int el = 8 * w + (l & 7);            // this wave's 8 edges
    float v = red[par][l >> 3][el];            // lane group = source wave
    v += __shfl_xor(v, 8);
    v += __shfl_xor(v, 16);
    v += __shfl_xor(v, 32);
    const int eg = tile * EPT + el;
    if (l < 8 && eg < N_EDGES)
      out[eg] = 1.f / (1.f + __expf(-(v + b2v)));
  };

  // ---- prologue: stage t0, t0+G; prefetch idx for t0+2G; full drain ONCE ----
  const int t0 = blockIdx.x;
  stage(0, ldidx(t0));
  stage(1, ldidx(t0 + GRID_MAIN));
  int iv_b = ldidx(t0 + 2 * GRID_MAIN);
  asm volatile("s_waitcnt vmcnt(0) lgkmcnt(0)" ::: "memory");
  __builtin_amdgcn_s_barrier();
  asm volatile("" ::: "memory");

  int it = 0;
  for (int t = t0; t < NTILES; t += GRID_MAIN, ++it) {
    // 1) index load FIRST (so its later use only forces a counted wait)
    const int iv_c = ldidx(t + 3 * GRID_MAIN);
    // 2) stage tile t+2 into buf (it+2)&3 (WAR-safe: last read at iter it-2,
    //    whose ds_reads were lgkmcnt(0)-drained before iter it-1's barrier)
    stage((it + 2) & 3, iv_b);
    // 3) counted wait, NEVER 0. Queue audit (steady state, 6 vmem ops/iter):
    //    18 outstanding here; vmcnt(10) retires through tile(t-1)'s idx load,
    //    guaranteeing tile t's stage (issued at iter it-2) has landed while
    //    keeping tile(t+1)'s stage + tile(t+2)'s 5 ops + 1 store in flight.
    //    Transient iter 2 (16 outstanding, iter-0 had no store): retires
    //    iter-0's stage fully. vmcnt(12) would leave 1 chunk unretired there.
    asm volatile("s_waitcnt vmcnt(10) lgkmcnt(0)" ::: "memory");
    __builtin_amdgcn_sched_barrier(0);
    __builtin_amdgcn_s_barrier();
    __builtin_amdgcn_sched_barrier(0);
    asm volatile("" ::: "memory");

    // 4) deferred output for tile t-1
    if (it) emit(t - GRID_MAIN, (it - 1) & 1);

    // 5) MFMA: D[n][m] += sum_k A[n][k] * F[m][k] on buf it&3
    f32x4 acc[2][4];
    #pragma unroll
    for (int rt = 0; rt < 2; ++rt)
      #pragma unroll
      for (int ct = 0; ct < 4; ++ct)
        acc[rt][ct] = (f32x4){0.f, 0.f, 0.f, 0.f};

    const unsigned char* sb = &sbuf[it & 3][0];
    #pragma unroll
    for (int ks = 0; ks < 8; ++ks) {
      bf16x8 bf[4];
      #pragma unroll
      for (int ct = 0; ct < 4; ++ct) {
        const int c = ks * 4 + g;                    // k-chunk
        const int m = ct * 16 + l15;                 // edge
        bf[ct] = *(const bf16x8*)(sb + (c << 10) + (m << 4));
      }
      __builtin_amdgcn_s_setprio(1);
      #pragma unroll
      for (int rt = 0; rt < 2; ++rt)
        #pragma unroll
        for (int ct = 0; ct < 4; ++ct)
          acc[rt][ct] = __builtin_amdgcn_mfma_f32_16x16x32_bf16(
              a[rt][ks], bf[ct], acc[rt][ct], 0, 0, 0);
      __builtin_amdgcn_s_setprio(0);
    }

    // 6) epilogue: bias + relu + fc2 partial dot -> red[it&1]
    float p[4] = {0.f, 0.f, 0.f, 0.f};
    #pragma unroll
    for (int rt = 0; rt < 2; ++rt) {
      const int nb = w * 32 + rt * 16 + g * 4;
      const f32x4 bb = *(const f32x4*)&b1f[nb];
      const f32x4 ww = *(const f32x4*)&w2f[nb];
      #pragma unroll
      for (int r = 0; r < 4; ++r) {
        #pragma unroll
        for (int ct = 0; ct < 4; ++ct) {
          float x = acc[rt][ct][r] + bb[r];          // n = w*32+rt*16+g*4+r
          x = fmaxf(x, 0.f);
          p[ct] = fmaf(x, ww[r], p[ct]);
        }
      }
    }
    #pragma unroll
    for (int ct = 0; ct < 4; ++ct) {                 // sum over 4 g-groups
      p[ct] += __shfl_xor(p[ct], 16);
      p[ct] += __shfl_xor(p[ct], 32);
    }
    if (l < 16) {
      #pragma unroll
      for (int ct = 0; ct < 4; ++ct) red[it & 1][w][ct * 16 + l] = p[ct];
    }

    iv_b = iv_c;
  }

  // ---- tail: output last tile ----
  asm volatile("s_waitcnt lgkmcnt(0)" ::: "memory");
  __builtin_amdgcn_s_barrier();
  asm volatile("" ::: "memory");
  emit(t0 + (it - 1) * GRID_MAIN, (it - 1) & 1);
}

extern "C" void kernel_launch(void* const* d_in, const int* in_sizes, int n_in,
                              void* d_out, int out_size, void* d_ws, size_t ws_size,
                              hipStream_t stream) {
  const float* z    = (const float*)d_in[0];
  const int*   eidx = (const int*)d_in[1];
  const float* fc1w = (const float*)d_in[2];
  const float* fc1b = (const float*)d_in[3];
  const float* fc2w = (const float*)d_in[4];
  const float* fc2b = (const float*)d_in[5];
  float* out = (float*)d_out;

  unsigned short* z16 = (unsigned short*)d_ws;   // 25.6 MB bf16 copy of z

  cvt_z<<<2048, 256, 0, stream>>>(z, z16, N_NODES * D_FEAT / 4);
  mlp_main<<<GRID_MAIN, 512, 0, stream>>>(eidx, z16, fc1w, fc1b, fc2w, fc2b, out);
}

// Round 7
// 183.515 us; speedup vs baseline: 1.2044x; 1.0023x over previous
//
#include <hip/hip_runtime.h>
#include <stdint.h>

#define N_NODES 100000
#define D_FEAT  128
#define N_EDGES 500000
#define HIDDEN  256
#define EPT     32                                   // edges per tile
#define NTILES  (N_EDGES / EPT)                      // 15625, exact
#define GRID_MAIN 512                                // 2 blocks/CU

typedef __bf16 bf16x8 __attribute__((ext_vector_type(8)));
typedef __bf16 bf16x4 __attribute__((ext_vector_type(4)));
typedef float  f32x4  __attribute__((ext_vector_type(4)));

__device__ __forceinline__ void gld_lds16(const unsigned short* g, unsigned char* l) {
  __builtin_amdgcn_global_load_lds(
      (const __attribute__((address_space(1))) unsigned int*)g,
      (__attribute__((address_space(3))) unsigned int*)l, 16, 0, 0);
}

__device__ __forceinline__ bf16x8 cvt8(f32x4 lo, f32x4 hi) {
  bf16x8 r;
  r[0] = (__bf16)lo[0]; r[1] = (__bf16)lo[1]; r[2] = (__bf16)lo[2]; r[3] = (__bf16)lo[3];
  r[4] = (__bf16)hi[0]; r[5] = (__bf16)hi[1]; r[6] = (__bf16)hi[2]; r[7] = (__bf16)hi[3];
  return r;
}

// z (f32) -> bf16, vectorized
__global__ void cvt_z(const float* __restrict__ src, unsigned short* __restrict__ dst, int n4) {
  int i = blockIdx.x * blockDim.x + threadIdx.x;
  const int stride = gridDim.x * blockDim.x;
  for (; i < n4; i += stride) {
    const f32x4 v = ((const f32x4*)src)[i];
    bf16x4 o;
    o[0] = (__bf16)v[0]; o[1] = (__bf16)v[1]; o[2] = (__bf16)v[2]; o[3] = (__bf16)v[3];
    ((bf16x4*)dst)[i] = o;
  }
}

// xT = relu(W1 * concatT + b1); out = sigmoid(w2 . x + b2)
// 4 waves/block; wave w owns hidden rows [64w, 64w+64) (a[4][8] resident),
// covers all 32 edges. K-major LDS unit: sbuf[c*1024 + l*16] =
// F[l&31][c*16 + (l>>5)*8 .. +7]  (c = k-chunk 0..15, lane = edge + k-sub).
// Triple buffer, ONE barrier/tile, counted vmcnt(7), 2 blocks/CU.
__global__ __launch_bounds__(256, 2)
void mlp_main(const int* __restrict__ eidx,
              const unsigned short* __restrict__ z16,   // [N_NODES][128] bf16
              const float* __restrict__ w1f,            // [256][256] f32
              const float* __restrict__ b1,
              const float* __restrict__ w2g,
              const float* __restrict__ b2,
              float* __restrict__ out,
              float* __restrict__ dump) {
  __shared__ unsigned char sbuf[3][EPT * 512];          // 3 x 16 KiB
  __shared__ float red[2][4][40];                       // parity x wave x edge(pad)

  const int tid  = threadIdx.x;
  const int w    = tid >> 6;         // wave 0..3 (hidden group of 64)
  const int l    = tid & 63;
  const int l15  = l & 15;
  const int l31  = l & 31;
  const int g    = l >> 4;           // k-slice group 0..3
  const int half = w >> 1;           // staging half: 0 = row node, 1 = col node

  const int is64 = (eidx[1] == 0 && eidx[3] == 0 && eidx[5] == 0);
  const float b2v = b2[0];
  const int estride = is64 ? 6 : 3;
  const int eoff    = is64 ? (2 + 2 * half) : (1 + half);

  // ---- A fragments (W1, f32 -> bf16), resident: 128 regs ----
  // A[n][k]: n = w*64 + nt*16 + (l&15), k = ks*32 + g*8 .. +7
  bf16x8 a[4][8];
  #pragma unroll
  for (int nt = 0; nt < 4; ++nt) {
    const int n = w * 64 + nt * 16 + l15;
    #pragma unroll
    for (int ks = 0; ks < 8; ++ks) {
      const int k = ks * 32 + g * 8;
      const f32x4 lo = *(const f32x4*)(w1f + n * 256 + k);
      const f32x4 hi = *(const f32x4*)(w1f + n * 256 + k + 4);
      a[nt][ks] = cvt8(lo, hi);
    }
  }
  // bias / fc2 weights for this lane's accumulator rows (C/D row = g*4 + r)
  f32x4 b1v[4], w2v[4];
  #pragma unroll
  for (int nt = 0; nt < 4; ++nt) {
    const int nb = w * 64 + nt * 16 + g * 4;
    b1v[nt] = *(const f32x4*)(b1 + nb);
    w2v[nt] = *(const f32x4*)(w2g + nb);
  }

  // per-lane node index (this wave's half) for tile t; lane -> edge l&31
  auto ldidx = [&](int t) -> int {
    int e = t * EPT + l31;
    if (e > N_EDGES - 1) e = N_EDGES - 1;
    return eidx[e * estride + eoff];
  };
  // stage one tile: wave w issues chunks 4w..4w+3 (1 KiB each, linear dest)
  auto stage = [&](int buf, int iv) {
    const unsigned short* src = z16 + (size_t)iv * D_FEAT;
    #pragma unroll
    for (int j = 0; j < 4; ++j) {
      const int c = 4 * w + j;                 // chunks 0-7: row, 8-15: col
      gld_lds16(src + ((c & 7) << 4) + ((l >> 5) << 3), &sbuf[buf][c << 10]);
    }
  };

  // cross-wave sum + sigmoid for a finished tile; always ONE store per lane<8
  auto emit = [&](int tile, int par, bool real) {
    const int m  = 8 * w + (l & 7);            // this wave's 8 edges
    float v = red[par][(l >> 3) & 3][m];       // lane group = source wave
    v += __shfl_xor(v, 8);
    v += __shfl_xor(v, 16);
    const float s = 1.f / (1.f + __expf(-(v + b2v)));
    float* dst = real ? (out + tile * EPT + m) : (dump + blockIdx.x * EPT + m);
    if (l < 8) *dst = s;
  };

  // ---- prologue: stage t0; prefetch idx t0+G, t0+2G; pass-visible drain ----
  const int t0 = blockIdx.x;
  stage(0, ldidx(t0));
  int iv_b = ldidx(t0 + GRID_MAIN);
  int iv_c = ldidx(t0 + 2 * GRID_MAIN);
  __builtin_amdgcn_s_waitcnt(0);               // full drain (compiler-visible)

  int it = 0, cb = 0;
  for (int t = t0; t < NTILES; t += GRID_MAIN, ++it) {
    // 1) stage tile t+1 (iv_b loaded 2 iters ago -> compiler wait is counted)
    int cn = cb + 1; if (cn == 3) cn = 0;
    stage(cn, iv_b);
    // 2) idx prefetch for t+3
    const int iv_d = ldidx(t + 3 * GRID_MAIN);
    // 3) counted wait: 6 vmem ops/iter {stage 4, idx 1, store 1}; at this
    //    point newest 7 = {idx(t+2), store(t-2), stage(t+1) x4, idx(t+3)} ->
    //    vmcnt(7) retires stage(t) exactly. NEVER 0 in loop.
    asm volatile("s_waitcnt vmcnt(7) lgkmcnt(0)" ::: "memory");
    __builtin_amdgcn_sched_barrier(0);
    __builtin_amdgcn_s_barrier();
    __builtin_amdgcn_sched_barrier(0);

    // 4) deferred output for tile t-1 (dummy store to dump at it==0)
    emit(t - GRID_MAIN, (it - 1) & 1, it != 0);

    // 5) MFMA: D[n][m] += sum_k A[n][k] * F[m][k] on buf cb
    f32x4 acc[4][2];
    #pragma unroll
    for (int nt = 0; nt < 4; ++nt) {
      acc[nt][0] = (f32x4){0.f, 0.f, 0.f, 0.f};
      acc[nt][1] = (f32x4){0.f, 0.f, 0.f, 0.f};
    }
    const unsigned char* sb = &sbuf[cb][0];
    const int off0 = ((g >> 1) << 10) + ((g & 1) << 9) + (l15 << 4);
    #pragma unroll
    for (int ks = 0; ks < 8; ++ks) {
      bf16x8 bf[2];
      #pragma unroll
      for (int ct = 0; ct < 2; ++ct)           // conflict-free ds_read_b128
        bf[ct] = *(const bf16x8*)(sb + (ks << 11) + (ct << 8) + off0);
      __builtin_amdgcn_s_setprio(1);
      #pragma unroll
      for (int nt = 0; nt < 4; ++nt)
        #pragma unroll
        for (int ct = 0; ct < 2; ++ct)
          acc[nt][ct] = __builtin_amdgcn_mfma_f32_16x16x32_bf16(
              a[nt][ks], bf[ct], acc[nt][ct], 0, 0, 0);
      __builtin_amdgcn_s_setprio(0);
    }

    // 6) epilogue: bias + relu + fc2 partial dot -> red[it&1]
    float p[2] = {0.f, 0.f};
    #pragma unroll
    for (int nt = 0; nt < 4; ++nt) {
      #pragma unroll
      for (int r = 0; r < 4; ++r) {
        const float bb = b1v[nt][r], ww = w2v[nt][r];
        #pragma unroll
        for (int ct = 0; ct < 2; ++ct) {
          float x = acc[nt][ct][r] + bb;       // n = w*64+nt*16+g*4+r
          x = fmaxf(x, 0.f);
          p[ct] = fmaf(x, ww, p[ct]);
        }
      }
    }
    #pragma unroll
    for (int ct = 0; ct < 2; ++ct) {           // sum over 4 g-groups
      p[ct] += __shfl_xor(p[ct], 16);
      p[ct] += __shfl_xor(p[ct], 32);
    }
    if (l < 16) {
      red[it & 1][w][l15]      = p[0];
      red[it & 1][w][16 + l15] = p[1];
    }

    iv_b = iv_c; iv_c = iv_d; cb = cn;
  }

  // ---- tail: output last tile ----
  asm volatile("s_waitcnt lgkmcnt(0)" ::: "memory");
  __builtin_amdgcn_s_barrier();
  emit(t0 + (it - 1) * GRID_MAIN, (it - 1) & 1, true);
}

extern "C" void kernel_launch(void* const* d_in, const int* in_sizes, int n_in,
                              void* d_out, int out_size, void* d_ws, size_t ws_size,
                              hipStream_t stream) {
  const float* z    = (const float*)d_in[0];
  const int*   eidx = (const int*)d_in[1];
  const float* fc1w = (const float*)d_in[2];
  const float* fc1b = (const float*)d_in[3];
  const float* fc2w = (const float*)d_in[4];
  const float* fc2b = (const float*)d_in[5];
  float* out = (float*)d_out;

  unsigned short* z16 = (unsigned short*)d_ws;       // 25.6 MB bf16 copy of z
  float* dump = (float*)((unsigned char*)d_ws + 25600000);  // 64 KB scratch

  cvt_z<<<2048, 256, 0, stream>>>(z, z16, N_NODES * D_FEAT / 4);
  mlp_main<<<GRID_MAIN, 256, 0, stream>>>(eidx, z16, fc1w, fc1b, fc2w, fc2b,
                                          out, dump);
}